// Round 2
// baseline (118.504 us; speedup 1.0000x reference)
//
#include <hip/hip_runtime.h>
#include <stdint.h>

#define CI 256
#define CO 256
#define HW 4096          // 64*64 pixels per image
#define PT 64            // pixel tile per block (4 waves x 16 pixels)

typedef __attribute__((ext_vector_type(8))) short short8;   // 8 bf16 = 4 VGPRs
typedef __attribute__((ext_vector_type(4))) float float4v;  // MFMA C/D frag

// ---------- weight prep: fp32 -> bf16 (RNE) + per-row fp32 sums ----------
__global__ void prep_kernel(const float* __restrict__ w,
                            ushort* __restrict__ w16,
                            float* __restrict__ wsum) {
    const int o = blockIdx.x;        // one output row per 64-thread block
    const int lane = threadIdx.x;    // 0..63
    float4 v = ((const float4*)(w + o * CI))[lane];
    auto cvt = [](float f) -> ushort {
        uint32_t u = __float_as_uint(f);
        return (ushort)((u + 0x7FFFu + ((u >> 16) & 1u)) >> 16);   // RNE
    };
    ushort4 q;
    q.x = cvt(v.x); q.y = cvt(v.y); q.z = cvt(v.z); q.w = cvt(v.w);
    ((ushort4*)(w16 + o * CI))[lane] = q;
    float s = v.x + v.y + v.z + v.w;
    for (int off = 32; off >= 1; off >>= 1) s += __shfl_down(s, off);
    if (lane == 0) wsum[o] = s;
}

// ---------- fused quantize + 1x1-conv GEMM: no LDS, no barriers ----------
// Wave owns 16 pixels x 256 output channels.
// MFMA 16x16x32: A = quantized pixels (m=pixel), B = bf16 weights (n=out-ch).
// A-frag: A[m=lane&15][k=quad*8+j]; D: col(lane&15)=out-ch, row(quad*4+reg)=pixel.
__global__ __launch_bounds__(256)
void noise_conv_kernel(const float* __restrict__ x,
                       const ushort* __restrict__ w16,
                       const float* __restrict__ wsum,
                       const float* __restrict__ bias,
                       float* __restrict__ out) {
    const int t = threadIdx.x;
    const int lane = t & 63;
    const int wv = t >> 6;           // wave 0..3 -> pixels [16*wv, 16*wv+16)
    const int n16 = lane & 15;
    const int quad = lane >> 4;

    const int blk = blockIdx.x;      // 512 = 8 imgs * 64 tiles
    const int img = blk >> 6;
    const int p0 = (blk & 63) * PT;
    const int pix = p0 + wv * 16 + n16;          // this lane's pixel
    const float* xb = x + (size_t)img * CI * HW;

    // ---- load this lane's 64 channels (its A-frag slice): c = quad*8 + 32t + j
    float xv[64];
    #pragma unroll
    for (int tt = 0; tt < 8; ++tt)
        #pragma unroll
        for (int j = 0; j < 8; ++j)
            xv[tt * 8 + j] = xb[(size_t)(quad * 8 + 32 * tt + j) * HW + pix];

    // ---- per-pixel min/max: 63 in-reg pairs + 2 shuffles (lanes p,p+16,p+32,p+48)
    float mn = xv[0], mx = xv[0];
    #pragma unroll
    for (int i = 1; i < 64; ++i) { mn = fminf(mn, xv[i]); mx = fmaxf(mx, xv[i]); }
    mn = fminf(mn, __shfl_xor(mn, 16));
    mx = fmaxf(mx, __shfl_xor(mx, 16));
    mn = fminf(mn, __shfl_xor(mn, 32));
    mx = fmaxf(mx, __shfl_xor(mx, 32));

    const float cm = mn;
    const float sc = (mx - mn) / 63.0f;          // match ref: /63
    const float iv = 1.0f / sc;

    // ---- quantize in-register to bf16 A-frags (q in [0,63] exact in bf16)
    short8 afr[8];
    #pragma unroll
    for (int tt = 0; tt < 8; ++tt) {
        union { short8 s; uint32_t u[4]; } fr;
        #pragma unroll
        for (int j2 = 0; j2 < 4; ++j2) {
            const float q0 = rintf((xv[tt * 8 + 2 * j2]     - cm) * iv);
            const float q1 = rintf((xv[tt * 8 + 2 * j2 + 1] - cm) * iv);
            fr.u[j2] = (__float_as_uint(q0) >> 16) |
                       (__float_as_uint(q1) & 0xFFFF0000u);
        }
        afr[tt] = fr.s;
    }

    // ---- K-loop: 8 k-steps x 16 channel-tiles, weight frags straight from L1/L2
    float4v acc[16];
    #pragma unroll
    for (int nt = 0; nt < 16; ++nt) {
        float4v z = {0.0f, 0.0f, 0.0f, 0.0f};
        acc[nt] = z;
    }
    #pragma unroll
    for (int tt = 0; tt < 8; ++tt) {
        const short8 af = afr[tt];
        #pragma unroll
        for (int nt = 0; nt < 16; ++nt) {
            const short8 bf = *((const short8*)(
                w16 + (size_t)(nt * 16 + n16) * CI + tt * 32 + quad * 8));
            acc[nt] = __builtin_amdgcn_mfma_f32_16x16x32_bf16(af, bf, acc[nt], 0, 0, 0);
        }
    }

    // ---- epilogue: per-pixel rescale + cmin*wsum + bias, float4 stores
    float sv[4], cv[4];
    #pragma unroll
    for (int r = 0; r < 4; ++r) {                // D row r -> pixel quad*4+r
        sv[r] = __shfl(sc, quad * 4 + r);
        cv[r] = __shfl(cm, quad * 4 + r);
    }
    float* outb = out + (size_t)img * CO * HW + p0 + wv * 16 + quad * 4;
    #pragma unroll
    for (int nt = 0; nt < 16; ++nt) {
        const int ch = nt * 16 + n16;
        const float ws = wsum[ch];
        const float bs = bias[ch];
        float4 o;
        o.x = acc[nt][0] * sv[0] + cv[0] * ws + bs;
        o.y = acc[nt][1] * sv[1] + cv[1] * ws + bs;
        o.z = acc[nt][2] * sv[2] + cv[2] * ws + bs;
        o.w = acc[nt][3] * sv[3] + cv[3] * ws + bs;
        *((float4*)(outb + (size_t)ch * HW)) = o;
    }
}

extern "C" void kernel_launch(void* const* d_in, const int* in_sizes, int n_in,
                              void* d_out, int out_size, void* d_ws, size_t ws_size,
                              hipStream_t stream) {
    const float* x    = (const float*)d_in[0];
    const float* w    = (const float*)d_in[1];
    const float* bias = (const float*)d_in[2];
    float* out = (float*)d_out;

    ushort* w16 = (ushort*)d_ws;                                   // 128 KiB
    float* wsum = (float*)((char*)d_ws + (size_t)CO * CI * sizeof(ushort));

    prep_kernel<<<CO, 64, 0, stream>>>(w, w16, wsum);
    noise_conv_kernel<<<512, 256, 0, stream>>>(x, w16, wsum, bias, out);
}

// Round 4
// 101.365 us; speedup vs baseline: 1.1691x; 1.1691x over previous
//
#include <hip/hip_runtime.h>
#include <stdint.h>

#define CI 256
#define CO 256
#define HW 4096          // 64*64 pixels per image
#define PXT 32           // pixels per block (two MFMA m-tiles)
#define QP 264           // LDS Q row pitch in shorts (132 words; 16B-aligned rows)

typedef __attribute__((ext_vector_type(8))) short short8;   // 8 bf16 = 4 VGPRs
typedef __attribute__((ext_vector_type(4))) float float4v;  // MFMA C/D frag

// ---------- weight prep: fp32 -> bf16 (RNE) + per-row fp32 sums ----------
__global__ void prep_kernel(const float* __restrict__ w,
                            ushort* __restrict__ w16,
                            float* __restrict__ wsum) {
    const int o = blockIdx.x;        // one output row per 64-thread block
    const int lane = threadIdx.x;    // 0..63
    float4 v = ((const float4*)(w + o * CI))[lane];
    auto cvt = [](float f) -> ushort {
        uint32_t u = __float_as_uint(f);
        return (ushort)((u + 0x7FFFu + ((u >> 16) & 1u)) >> 16);   // RNE
    };
    ushort4 q;
    q.x = cvt(v.x); q.y = cvt(v.y); q.z = cvt(v.z); q.w = cvt(v.w);
    ((ushort4*)(w16 + o * CI))[lane] = q;
    float s = v.x + v.y + v.z + v.w;
    for (int off = 32; off >= 1; off >>= 1) s += __shfl_down(s, off);
    if (lane == 0) wsum[o] = s;
}

// ---------- fused: x read ONCE -> min/max -> quantize -> MFMA GEMM ----------
// block = 32 px x 256 out-ch (1024 blocks, 4/CU); wave = 32 px x 64 out-ch.
// MFMA 16x16x32: A = quantized pixels, B = bf16 weights.
// A-frag A[m=lane&15][k=quad*8+j]; D: col(lane&15)=ch, row(quad*4+reg)=pixel.
__global__ __launch_bounds__(256)
void noise_conv_kernel(const float* __restrict__ x,
                       const ushort* __restrict__ w16,
                       const float* __restrict__ wsum,
                       const float* __restrict__ bias,
                       float* __restrict__ out) {
    __shared__ ushort Q[PXT * QP];             // ~16.9 KB quantized bf16 tile
    __shared__ float Rmn[8][33], Rmx[8][33];   // per-(channel-group, pixel) partials
    __shared__ float cmin_s[PXT], s_s[PXT], inv_s[PXT];

    const int t = threadIdx.x;
    const int blk = blockIdx.x;                // 1024 = 8 img * 128 tiles
    const int img = blk >> 7;
    const int p0 = (blk & 127) * PXT;
    const float* xb = x + (size_t)img * CI * HW + p0;

    const int p = t & 31;                      // this thread's pixel (0..31)
    const int cg = t >> 5;                     // channel group (32 ch each), 0..7

    // ---- load this thread's 32 channels of its pixel (x read once) ----
    float xv[32];
    #pragma unroll
    for (int j = 0; j < 32; ++j)
        xv[j] = xb[(size_t)(cg * 32 + j) * HW + p];

    // ---- per-pixel min/max: 31 local pairs + 8-way LDS reduce ----
    float mn = xv[0], mx = xv[0];
    #pragma unroll
    for (int j = 1; j < 32; ++j) { mn = fminf(mn, xv[j]); mx = fmaxf(mx, xv[j]); }
    Rmn[cg][p] = mn;
    Rmx[cg][p] = mx;
    __syncthreads();
    if (t < 32) {
        float m0 = Rmn[0][t], m1 = Rmx[0][t];
        #pragma unroll
        for (int s = 1; s < 8; ++s) {
            m0 = fminf(m0, Rmn[s][t]);
            m1 = fmaxf(m1, Rmx[s][t]);
        }
        const float sc = (m1 - m0) / 63.0f;    // match ref: /63
        cmin_s[t] = m0;
        s_s[t] = sc;
        inv_s[t] = 1.0f / sc;
    }
    __syncthreads();

    // ---- quantize in-register to bf16 (q in [0,63] exact), stage to LDS ----
    {
        const float cm = cmin_s[p];
        const float iv = inv_s[p];
        uint32_t pk[16];
        #pragma unroll
        for (int j2 = 0; j2 < 16; ++j2) {
            const float q0 = rintf((xv[2 * j2]     - cm) * iv);
            const float q1 = rintf((xv[2 * j2 + 1] - cm) * iv);
            pk[j2] = (__float_as_uint(q0) >> 16) |
                     (__float_as_uint(q1) & 0xFFFF0000u);   // exact bf16 pack
        }
        ushort* qrow = Q + p * QP + cg * 32;
        #pragma unroll
        for (int v = 0; v < 4; ++v)
            ((uint4*)qrow)[v] = make_uint4(pk[4 * v], pk[4 * v + 1],
                                           pk[4 * v + 2], pk[4 * v + 3]);
    }
    __syncthreads();

    // ---- K-loop: A from LDS (2 m-tiles), B from L2-resident weights ----
    const int l = t & 63;
    const int wv = t >> 6;                     // wave -> out-ch [64wv, 64wv+64)
    const int m16 = l & 15;
    const int quad = l >> 4;

    float4v acc[2][4];
    #pragma unroll
    for (int mt = 0; mt < 2; ++mt)
        #pragma unroll
        for (int nt = 0; nt < 4; ++nt) {
            float4v z = {0.0f, 0.0f, 0.0f, 0.0f};
            acc[mt][nt] = z;
        }

    const ushort* wrow = w16 + (size_t)(wv * 64) * CI;
    #pragma unroll
    for (int ks = 0; ks < 8; ++ks) {
        short8 af[2];
        #pragma unroll
        for (int mt = 0; mt < 2; ++mt)
            af[mt] = *((const short8*)(
                Q + (mt * 16 + m16) * QP + ks * 32 + quad * 8));
        #pragma unroll
        for (int nt = 0; nt < 4; ++nt) {
            const short8 bf = *((const short8*)(
                wrow + (size_t)(nt * 16 + m16) * CI + ks * 32 + quad * 8));
            #pragma unroll
            for (int mt = 0; mt < 2; ++mt)
                acc[mt][nt] = __builtin_amdgcn_mfma_f32_16x16x32_bf16(
                    af[mt], bf, acc[mt][nt], 0, 0, 0);
        }
    }

    // ---- epilogue: rescale + cmin*wsum + bias, float4 stores ----
    float* outp = out + (size_t)img * CO * HW + p0;
    #pragma unroll
    for (int mt = 0; mt < 2; ++mt) {
        const int pb = mt * 16 + quad * 4;     // pixel base for D rows 0..3
        float sv[4], cv[4];
        #pragma unroll
        for (int r = 0; r < 4; ++r) {
            sv[r] = s_s[pb + r];
            cv[r] = cmin_s[pb + r];
        }
        #pragma unroll
        for (int nt = 0; nt < 4; ++nt) {
            const int ch = wv * 64 + nt * 16 + m16;
            const float ws = wsum[ch];
            const float bs = bias[ch];
            float4 o;
            o.x = acc[mt][nt][0] * sv[0] + cv[0] * ws + bs;
            o.y = acc[mt][nt][1] * sv[1] + cv[1] * ws + bs;
            o.z = acc[mt][nt][2] * sv[2] + cv[2] * ws + bs;
            o.w = acc[mt][nt][3] * sv[3] + cv[3] * ws + bs;
            *((float4*)(outp + (size_t)ch * HW + pb)) = o;
        }
    }
}

extern "C" void kernel_launch(void* const* d_in, const int* in_sizes, int n_in,
                              void* d_out, int out_size, void* d_ws, size_t ws_size,
                              hipStream_t stream) {
    const float* x    = (const float*)d_in[0];
    const float* w    = (const float*)d_in[1];
    const float* bias = (const float*)d_in[2];
    float* out = (float*)d_out;

    ushort* w16 = (ushort*)d_ws;                                   // 128 KiB
    float* wsum = (float*)((char*)d_ws + (size_t)CO * CI * sizeof(ushort));

    prep_kernel<<<CO, 64, 0, stream>>>(w, w16, wsum);
    noise_conv_kernel<<<1024, 256, 0, stream>>>(x, w16, wsum, bias, out);
}